// Round 1
// baseline (603.770 us; speedup 1.0000x reference)
//
#include <hip/hip_runtime.h>
#include <hip/hip_bf16.h>
#include <stdint.h>

#define HH   1024
#define FF   1024
#define NE   32
#define NK   4
#define CAP  256
#define BK   32
#define TN   192

typedef __bf16 bf16x8 __attribute__((ext_vector_type(8)));
typedef __bf16 bf16x4 __attribute__((ext_vector_type(4)));
typedef __bf16 bf16x2 __attribute__((ext_vector_type(2)));
typedef float  f32x4v __attribute__((ext_vector_type(4)));

// ---------------- workspace layout (bytes) ----------------
// cnt      @ 0        : 32 * 4
// toklist  @ 1024     : 32*256*4   = 32768
// wgtlist  @ 33792    : 32*256*4   = 32768   (ends 66560)
// t_bf16   @ 131072   : 1024*1024*2 = 2 MiB  (ends 2228224)
// h        @ 2228224  : 32*256*1024*2 = 16 MiB (ends ~18.1 MiB)
#define OFF_TOK 1024
#define OFF_WGT 33792
#define OFF_T   131072
#define OFF_H   2228224

__global__ void k_zero(int* __restrict__ cnt) {
    if (threadIdx.x < NE) cnt[threadIdx.x] = 0;
}

// ---------------- router: rmsnorm + gate + top4 + lists + residual init ----------------
__global__ __launch_bounds__(256) void k_router(
    const float* __restrict__ x, const float* __restrict__ nscale,
    const float* __restrict__ gw, const float* __restrict__ gb,
    float* __restrict__ out, __bf16* __restrict__ tbf,
    int* __restrict__ cnt, int* __restrict__ tok, float* __restrict__ wgt)
{
    const int t = blockIdx.x, tid = threadIdx.x;
    __shared__ float tl[HH];
    __shared__ float red[4];
    __shared__ float logits[NE];

    float4 xv = ((const float4*)(x + (size_t)t * HH))[tid];
    float ss = xv.x * xv.x + xv.y * xv.y + xv.z * xv.z + xv.w * xv.w;
    #pragma unroll
    for (int o = 32; o; o >>= 1) ss += __shfl_xor(ss, o);
    if ((tid & 63) == 0) red[tid >> 6] = ss;
    __syncthreads();
    const float mean = (red[0] + red[1] + red[2] + red[3]) * (1.0f / HH);
    const float r = rsqrtf(mean + 1e-5f);
    float4 sc = ((const float4*)nscale)[tid];
    float4 tv;
    tv.x = xv.x * r * sc.x; tv.y = xv.y * r * sc.y;
    tv.z = xv.z * r * sc.z; tv.w = xv.w * r * sc.w;

    ((float4*)(out + (size_t)t * HH))[tid] = xv;   // residual init: out = x
    ((float4*)tl)[tid] = tv;                       // fp32 t for gate
    bf16x4 pv = { (__bf16)tv.x, (__bf16)tv.y, (__bf16)tv.z, (__bf16)tv.w };
    *(bf16x4*)(tbf + (size_t)t * HH + tid * 4) = pv;
    __syncthreads();

    // gate: 8 threads per expert
    const int e = tid >> 3, q = tid & 7;
    const float4* gr = (const float4*)(gw + e * HH + q * 128);
    const float4* tr = (const float4*)(tl + q * 128);
    float s = 0.f;
    #pragma unroll 8
    for (int j = 0; j < 32; ++j) {
        float4 g = gr[j], v = tr[j];
        s += g.x * v.x + g.y * v.y + g.z * v.z + g.w * v.w;
    }
    s += __shfl_xor(s, 1); s += __shfl_xor(s, 2); s += __shfl_xor(s, 4);
    if (q == 0) logits[e] = s + gb[e];
    __syncthreads();

    if (tid == 0) {
        float v[NK]; int id[NK]; unsigned used = 0;
        for (int k = 0; k < NK; ++k) {
            float best = -1e30f; int bi = 0;
            for (int ee = 0; ee < NE; ++ee)
                if (!((used >> ee) & 1u) && logits[ee] > best) { best = logits[ee]; bi = ee; }
            used |= 1u << bi; v[k] = best; id[k] = bi;
        }
        float ex[NK], se = 0.f;
        for (int k = 0; k < NK; ++k) { ex[k] = __expf(v[k] - v[0]); se += ex[k]; }
        const float inv = 1.0f / se;
        for (int k = 0; k < NK; ++k) {
            int pos = atomicAdd(&cnt[id[k]], 1);
            if (pos < CAP) {
                tok[id[k] * CAP + pos] = t;
                wgt[id[k] * CAP + pos] = ex[k] * inv;
            }
        }
    }
}

// ---------------- mlp1: h = swiglu(t @ w1[e]^T + b1) * route_w, gathered per expert ----------------
// Orientation: MFMA m = w1 row (2048), n = token slot. Pairs (2u,2u+1) land in one lane.
__global__ __launch_bounds__(256, 2) void k_mlp1(
    const float* __restrict__ w1, const float* __restrict__ b1,
    const __bf16* __restrict__ tbf, const int* __restrict__ cnt,
    const int* __restrict__ tok, const float* __restrict__ wgt,
    __bf16* __restrict__ h)
{
    const int mtile = blockIdx.x;   // 16 tiles x 128 w1-rows
    const int e     = blockIdx.y;
    const int ntile = blockIdx.z;   // 2 tiles x 192 slots
    const int tid   = threadIdx.x;

    int Me = cnt[e]; Me = Me > CAP ? CAP : Me;
    const int n0 = ntile * TN;
    if (n0 >= Me) return;
    int MeL = Me - n0; MeL = MeL > TN ? TN : MeL;
    const int nreal = (MeL + 15) >> 4;

    __shared__ __bf16 Al[128 * BK];
    __shared__ __bf16 Bl[TN * BK];
    __shared__ float  wgtL[TN];

    int myTok = 0;
    if (tid < TN) {
        const int sl = n0 + tid;
        float w = 0.f;
        if (sl < Me) { myTok = tok[e * CAP + sl]; w = wgt[e * CAP + sl]; }
        wgtL[tid] = w;
    }

    f32x4v acc[8][3];
    #pragma unroll
    for (int s = 0; s < 8; ++s)
        #pragma unroll
        for (int j = 0; j < 3; ++j)
            #pragma unroll
            for (int q = 0; q < 4; ++q) acc[s][j][q] = 0.f;

    const float* wA = w1 + ((size_t)e * 2048 + (size_t)mtile * 128) * HH;
    const int arow = tid >> 1, ahalf = tid & 1;
    const int ars  = (arow >> 1) & 3;
    const int lane = tid & 63, wv = tid >> 6;
    const int mr = lane & 15, qd = lane >> 4;
    const int foff = mr * BK + ((qd ^ ((mr >> 1) & 3)) << 3);
    const __bf16* tbase = tbf + (size_t)myTok * HH;

    for (int ks = 0; ks < 32; ++ks) {
        __syncthreads();
        {   // stage A: 128 rows x 32 k of w1, fp32 -> bf16
            const float4* src = (const float4*)(wA + (size_t)arow * HH + ks * BK + ahalf * 16);
            float4 f0 = src[0], f1 = src[1], f2 = src[2], f3 = src[3];
            bf16x8 p0, p1;
            p0[0]=(__bf16)f0.x; p0[1]=(__bf16)f0.y; p0[2]=(__bf16)f0.z; p0[3]=(__bf16)f0.w;
            p0[4]=(__bf16)f1.x; p0[5]=(__bf16)f1.y; p0[6]=(__bf16)f1.z; p0[7]=(__bf16)f1.w;
            p1[0]=(__bf16)f2.x; p1[1]=(__bf16)f2.y; p1[2]=(__bf16)f2.z; p1[3]=(__bf16)f2.w;
            p1[4]=(__bf16)f3.x; p1[5]=(__bf16)f3.y; p1[6]=(__bf16)f3.z; p1[7]=(__bf16)f3.w;
            *(bf16x8*)&Al[arow * BK + (((2 * ahalf    ) ^ ars) << 3)] = p0;
            *(bf16x8*)&Al[arow * BK + (((2 * ahalf + 1) ^ ars) << 3)] = p1;
        }
        if (tid < TN) {   // stage B: gathered token rows (bf16 already)
            const uint4* src = (const uint4*)(tbase + ks * BK);
            uint4 c0 = src[0], c1 = src[1], c2 = src[2], c3 = src[3];
            const int rs = (tid >> 1) & 3;
            *(uint4*)&Bl[tid * BK + ((0 ^ rs) << 3)] = c0;
            *(uint4*)&Bl[tid * BK + ((1 ^ rs) << 3)] = c1;
            *(uint4*)&Bl[tid * BK + ((2 ^ rs) << 3)] = c2;
            *(uint4*)&Bl[tid * BK + ((3 ^ rs) << 3)] = c3;
        }
        __syncthreads();
        bf16x8 af[8];
        #pragma unroll
        for (int s = 0; s < 8; ++s) af[s] = *(const bf16x8*)&Al[s * 16 * BK + foff];
        #pragma unroll
        for (int j = 0; j < 3; ++j) {
            const int nsub = wv + j * 4;
            if (nsub < nreal) {
                bf16x8 bfr = *(const bf16x8*)&Bl[nsub * 16 * BK + foff];
                #pragma unroll
                for (int s = 0; s < 8; ++s)
                    acc[s][j] = __builtin_amdgcn_mfma_f32_16x16x32_bf16(af[s], bfr, acc[s][j], 0, 0, 0);
            }
        }
    }

    const size_t hbase = (size_t)e * CAP + n0;
    #pragma unroll
    for (int s = 0; s < 8; ++s) {
        const int rowb = mtile * 128 + s * 16 + qd * 4;   // even
        const float4 bv = *(const float4*)(b1 + e * 2048 + rowb);
        #pragma unroll
        for (int j = 0; j < 3; ++j) {
            const int nsub = wv + j * 4;
            const int slot = nsub * 16 + mr;
            if (nsub < nreal && slot < MeL) {
                f32x4v v = acc[s][j];
                const float wt = wgtL[slot];
                float g0 = v[0] + bv.x, l0 = v[1] + bv.y;
                float g1 = v[2] + bv.z, l1 = v[3] + bv.w;
                g0 = fminf(g0, 7.f);
                g1 = fminf(g1, 7.f);
                l0 = fminf(fmaxf(l0, -7.f), 7.f);
                l1 = fminf(fmaxf(l1, -7.f), 7.f);
                const float h0 = g0 * (1.f / (1.f + __expf(-1.702f * g0))) * (l0 + 1.f) * wt;
                const float h1 = g1 * (1.f / (1.f + __expf(-1.702f * g1))) * (l1 + 1.f) * wt;
                bf16x2 hv = { (__bf16)h0, (__bf16)h1 };
                *(bf16x2*)(h + (hbase + slot) * FF + (rowb >> 1)) = hv;
            }
        }
    }
}

// ---------------- mlp2: out[token] += h @ w2[e]^T + route_w*b2 ----------------
__global__ __launch_bounds__(256, 2) void k_mlp2(
    const float* __restrict__ w2, const float* __restrict__ b2,
    const __bf16* __restrict__ h, const int* __restrict__ cnt,
    const int* __restrict__ tok, const float* __restrict__ wgt,
    float* __restrict__ out)
{
    const int mtile = blockIdx.x;   // 16 tiles x 64 out-cols
    const int e     = blockIdx.y;
    const int ntile = blockIdx.z;
    const int tid   = threadIdx.x;

    int Me = cnt[e]; Me = Me > CAP ? CAP : Me;
    const int n0 = ntile * TN;
    if (n0 >= Me) return;
    int MeL = Me - n0; MeL = MeL > TN ? TN : MeL;
    const int nreal = (MeL + 15) >> 4;

    __shared__ __bf16 Al[64 * BK];
    __shared__ __bf16 Bl[TN * BK];
    __shared__ int    tokL[TN];
    __shared__ float  wgtL[TN];

    bool bval = false;
    if (tid < TN) {
        const int sl = n0 + tid;
        int tk = 0; float w = 0.f;
        if (sl < Me) { tk = tok[e * CAP + sl]; w = wgt[e * CAP + sl]; }
        tokL[tid] = tk; wgtL[tid] = w;
        bval = (sl < CAP);
    }
    const __bf16* hrow = h + ((size_t)e * CAP + n0 + tid) * FF;   // deref only if bval
    const float* wA = w2 + ((size_t)e * HH + (size_t)mtile * 64) * FF;

    f32x4v acc[4][3];
    #pragma unroll
    for (int s = 0; s < 4; ++s)
        #pragma unroll
        for (int j = 0; j < 3; ++j)
            #pragma unroll
            for (int q = 0; q < 4; ++q) acc[s][j][q] = 0.f;

    const int arow = tid >> 2, aq = tid & 3;
    const int ars  = (arow >> 1) & 3;
    const int lane = tid & 63, wv = tid >> 6;
    const int mr = lane & 15, qd = lane >> 4;
    const int foff = mr * BK + ((qd ^ ((mr >> 1) & 3)) << 3);

    for (int ks = 0; ks < 32; ++ks) {
        __syncthreads();
        {   // stage A: 64 rows x 32 k of w2, fp32 -> bf16
            const float4* src = (const float4*)(wA + (size_t)arow * FF + ks * BK + aq * 8);
            float4 f0 = src[0], f1 = src[1];
            bf16x8 p0;
            p0[0]=(__bf16)f0.x; p0[1]=(__bf16)f0.y; p0[2]=(__bf16)f0.z; p0[3]=(__bf16)f0.w;
            p0[4]=(__bf16)f1.x; p0[5]=(__bf16)f1.y; p0[6]=(__bf16)f1.z; p0[7]=(__bf16)f1.w;
            *(bf16x8*)&Al[arow * BK + ((aq ^ ars) << 3)] = p0;
        }
        if (bval) {   // stage B: gathered h rows (bf16, contiguous per expert)
            const uint4* src = (const uint4*)(hrow + ks * BK);
            uint4 c0 = src[0], c1 = src[1], c2 = src[2], c3 = src[3];
            const int rs = (tid >> 1) & 3;
            *(uint4*)&Bl[tid * BK + ((0 ^ rs) << 3)] = c0;
            *(uint4*)&Bl[tid * BK + ((1 ^ rs) << 3)] = c1;
            *(uint4*)&Bl[tid * BK + ((2 ^ rs) << 3)] = c2;
            *(uint4*)&Bl[tid * BK + ((3 ^ rs) << 3)] = c3;
        }
        __syncthreads();
        bf16x8 af[4];
        #pragma unroll
        for (int s = 0; s < 4; ++s) af[s] = *(const bf16x8*)&Al[s * 16 * BK + foff];
        #pragma unroll
        for (int j = 0; j < 3; ++j) {
            const int nsub = wv + j * 4;
            if (nsub < nreal) {
                bf16x8 bfr = *(const bf16x8*)&Bl[nsub * 16 * BK + foff];
                #pragma unroll
                for (int s = 0; s < 4; ++s)
                    acc[s][j] = __builtin_amdgcn_mfma_f32_16x16x32_bf16(af[s], bfr, acc[s][j], 0, 0, 0);
            }
        }
    }

    #pragma unroll
    for (int s = 0; s < 4; ++s) {
        const int colb = mtile * 64 + s * 16 + qd * 4;
        const float4 b2v = *(const float4*)(b2 + e * HH + colb);
        #pragma unroll
        for (int j = 0; j < 3; ++j) {
            const int nsub = wv + j * 4;
            const int slot = nsub * 16 + mr;
            if (nsub < nreal && slot < MeL) {
                const int token = tokL[slot];
                const float wt = wgtL[slot];
                float* op = out + (size_t)token * HH + colb;
                f32x4v v = acc[s][j];
                atomicAdd(op + 0, v[0] + wt * b2v.x);
                atomicAdd(op + 1, v[1] + wt * b2v.y);
                atomicAdd(op + 2, v[2] + wt * b2v.z);
                atomicAdd(op + 3, v[3] + wt * b2v.w);
            }
        }
    }
}

extern "C" void kernel_launch(void* const* d_in, const int* in_sizes, int n_in,
                              void* d_out, int out_size, void* d_ws, size_t ws_size,
                              hipStream_t stream) {
    const float* x      = (const float*)d_in[0];
    const float* nscale = (const float*)d_in[1];
    const float* gw     = (const float*)d_in[2];
    const float* gb     = (const float*)d_in[3];
    const float* w1     = (const float*)d_in[4];
    const float* b1     = (const float*)d_in[5];
    const float* w2     = (const float*)d_in[6];
    const float* b2     = (const float*)d_in[7];
    float* out = (float*)d_out;

    char* ws = (char*)d_ws;
    int*    cnt = (int*)(ws);
    int*    tok = (int*)(ws + OFF_TOK);
    float*  wgt = (float*)(ws + OFF_WGT);
    __bf16* tbf = (__bf16*)(ws + OFF_T);
    __bf16* h   = (__bf16*)(ws + OFF_H);

    k_zero<<<1, 64, 0, stream>>>(cnt);
    k_router<<<1024, 256, 0, stream>>>(x, nscale, gw, gb, out, tbf, cnt, tok, wgt);
    k_mlp1<<<dim3(16, 32, 2), 256, 0, stream>>>(w1, b1, tbf, cnt, tok, wgt, h);
    k_mlp2<<<dim3(16, 32, 2), 256, 0, stream>>>(w2, b2, h, cnt, tok, wgt, out);
}

// Round 2
// 561.306 us; speedup vs baseline: 1.0757x; 1.0757x over previous
//
#include <hip/hip_runtime.h>
#include <hip/hip_bf16.h>
#include <stdint.h>

#define HH   1024
#define FF   1024
#define NE   32
#define NK   4
#define CAP  256
#define BK   32
#define TN   192

typedef __bf16 bf16x8 __attribute__((ext_vector_type(8)));
typedef __bf16 bf16x4 __attribute__((ext_vector_type(4)));
typedef __bf16 bf16x2 __attribute__((ext_vector_type(2)));
typedef float  f32x4v __attribute__((ext_vector_type(4)));

// ---------------- workspace layout (bytes) ----------------
#define OFF_TOK 1024        // 32*256*4 = 32 KiB
#define OFF_WGT 33792       // 32 KiB
#define OFF_ES  66560       // 1024*4*4 = 16 KiB (packed e<<16|pos per token,k)
#define OFF_RW  82944       // 16 KiB (routing weight per token,k)
#define OFF_T   131072      // 2 MiB  bf16 t
#define OFF_H   2228224     // 16 MiB bf16 h (mlp1 out, per expert-slot)
#define OFF_H2  19005440    // 32 MiB fp32 h2 (mlp2 out, per expert-slot)

__global__ void k_zero(int* __restrict__ cnt) {
    if (threadIdx.x < NE) cnt[threadIdx.x] = 0;
}

// ---------------- router: rmsnorm + gate + top4 + lists ----------------
__global__ __launch_bounds__(256) void k_router(
    const float* __restrict__ x, const float* __restrict__ nscale,
    const float* __restrict__ gw, const float* __restrict__ gb,
    __bf16* __restrict__ tbf, int* __restrict__ cnt,
    int* __restrict__ tok, float* __restrict__ wgt,
    int* __restrict__ res, float* __restrict__ rw)
{
    const int t = blockIdx.x, tid = threadIdx.x;
    __shared__ float tl[HH];
    __shared__ float red[4];
    __shared__ float logits[NE];

    float4 xv = ((const float4*)(x + (size_t)t * HH))[tid];
    float ss = xv.x * xv.x + xv.y * xv.y + xv.z * xv.z + xv.w * xv.w;
    #pragma unroll
    for (int o = 32; o; o >>= 1) ss += __shfl_xor(ss, o);
    if ((tid & 63) == 0) red[tid >> 6] = ss;
    __syncthreads();
    const float mean = (red[0] + red[1] + red[2] + red[3]) * (1.0f / HH);
    const float r = rsqrtf(mean + 1e-5f);
    float4 sc = ((const float4*)nscale)[tid];
    float4 tv;
    tv.x = xv.x * r * sc.x; tv.y = xv.y * r * sc.y;
    tv.z = xv.z * r * sc.z; tv.w = xv.w * r * sc.w;

    ((float4*)tl)[tid] = tv;
    bf16x4 pv = { (__bf16)tv.x, (__bf16)tv.y, (__bf16)tv.z, (__bf16)tv.w };
    *(bf16x4*)(tbf + (size_t)t * HH + tid * 4) = pv;
    __syncthreads();

    const int e = tid >> 3, q = tid & 7;
    const float4* gr = (const float4*)(gw + e * HH + q * 128);
    const float4* tr = (const float4*)(tl + q * 128);
    float s = 0.f;
    #pragma unroll 8
    for (int j = 0; j < 32; ++j) {
        float4 g = gr[j], v = tr[j];
        s += g.x * v.x + g.y * v.y + g.z * v.z + g.w * v.w;
    }
    s += __shfl_xor(s, 1); s += __shfl_xor(s, 2); s += __shfl_xor(s, 4);
    if (q == 0) logits[e] = s + gb[e];
    __syncthreads();

    if (tid == 0) {
        float v[NK]; int id[NK]; unsigned used = 0;
        for (int k = 0; k < NK; ++k) {
            float best = -1e30f; int bi = 0;
            for (int ee = 0; ee < NE; ++ee)
                if (!((used >> ee) & 1u) && logits[ee] > best) { best = logits[ee]; bi = ee; }
            used |= 1u << bi; v[k] = best; id[k] = bi;
        }
        float ex[NK], se = 0.f;
        for (int k = 0; k < NK; ++k) { ex[k] = __expf(v[k] - v[0]); se += ex[k]; }
        const float inv = 1.0f / se;
        for (int k = 0; k < NK; ++k) {
            const float wk = ex[k] * inv;
            int pos = atomicAdd(&cnt[id[k]], 1);
            if (pos < CAP) {
                tok[id[k] * CAP + pos] = t;
                wgt[id[k] * CAP + pos] = wk;
            }
            res[t * NK + k] = (id[k] << 16) | (pos & 0xffff);
            rw[t * NK + k] = wk;
        }
    }
}

// ---------------- mlp1: h = swiglu(t @ w1[e]^T + b1) * route_w ----------------
// M-tile 64 w1-rows, N-tile 192 token slots, register-prefetch pipeline.
__global__ __launch_bounds__(256, 3) void k_mlp1(
    const float* __restrict__ w1, const float* __restrict__ b1,
    const __bf16* __restrict__ tbf, const int* __restrict__ cnt,
    const int* __restrict__ tok, const float* __restrict__ wgt,
    __bf16* __restrict__ h)
{
    const int mtile = blockIdx.x;   // 32 tiles x 64 w1-rows
    const int e     = blockIdx.y;
    const int ntile = blockIdx.z;
    const int tid   = threadIdx.x;

    int Me = cnt[e]; Me = Me > CAP ? CAP : Me;
    const int n0 = ntile * TN;
    if (n0 >= Me) return;
    int MeL = Me - n0; MeL = MeL > TN ? TN : MeL;
    const int nreal = (MeL + 15) >> 4;

    __shared__ __bf16 Al[64 * BK];
    __shared__ __bf16 Bl[TN * BK];
    __shared__ float  wgtL[TN];

    int myTok = 0;
    if (tid < TN) {
        const int sl = n0 + tid;
        float w = 0.f;
        if (sl < Me) { myTok = tok[e * CAP + sl]; w = wgt[e * CAP + sl]; }
        wgtL[tid] = w;
    }

    f32x4v acc[4][3];
    #pragma unroll
    for (int s = 0; s < 4; ++s)
        #pragma unroll
        for (int j = 0; j < 3; ++j)
            #pragma unroll
            for (int q = 0; q < 4; ++q) acc[s][j][q] = 0.f;

    const int arow = tid >> 2, aq = tid & 3;
    const int ars  = (arow >> 1) & 3;
    const int rs   = (tid >> 1) & 3;
    const int lane = tid & 63, wv = tid >> 6;
    const int mr = lane & 15, qd = lane >> 4;
    const int foff = mr * BK + ((qd ^ ((mr >> 1) & 3)) << 3);
    const float* aptr = w1 + ((size_t)e * 2048 + (size_t)mtile * 64 + arow) * HH + aq * 8;
    const __bf16* tbase = tbf + (size_t)myTok * HH;

    float4 pa0, pa1;
    uint4  pb0, pb1, pb2, pb3;
    pa0 = ((const float4*)aptr)[0];
    pa1 = ((const float4*)aptr)[1];
    if (tid < TN) {
        const uint4* bs = (const uint4*)tbase;
        pb0 = bs[0]; pb1 = bs[1]; pb2 = bs[2]; pb3 = bs[3];
    }

    for (int ks = 0; ks < 32; ++ks) {
        __syncthreads();
        {
            bf16x8 p0;
            p0[0]=(__bf16)pa0.x; p0[1]=(__bf16)pa0.y; p0[2]=(__bf16)pa0.z; p0[3]=(__bf16)pa0.w;
            p0[4]=(__bf16)pa1.x; p0[5]=(__bf16)pa1.y; p0[6]=(__bf16)pa1.z; p0[7]=(__bf16)pa1.w;
            *(bf16x8*)&Al[arow * BK + ((aq ^ ars) << 3)] = p0;
        }
        if (tid < TN) {
            *(uint4*)&Bl[tid * BK + ((0 ^ rs) << 3)] = pb0;
            *(uint4*)&Bl[tid * BK + ((1 ^ rs) << 3)] = pb1;
            *(uint4*)&Bl[tid * BK + ((2 ^ rs) << 3)] = pb2;
            *(uint4*)&Bl[tid * BK + ((3 ^ rs) << 3)] = pb3;
        }
        __syncthreads();
        if (ks < 31) {
            const float4* s2 = (const float4*)(aptr + (ks + 1) * BK);
            pa0 = s2[0]; pa1 = s2[1];
            if (tid < TN) {
                const uint4* bs = (const uint4*)(tbase + (ks + 1) * BK);
                pb0 = bs[0]; pb1 = bs[1]; pb2 = bs[2]; pb3 = bs[3];
            }
        }
        bf16x8 af[4];
        #pragma unroll
        for (int s = 0; s < 4; ++s) af[s] = *(const bf16x8*)&Al[s * 16 * BK + foff];
        #pragma unroll
        for (int j = 0; j < 3; ++j) {
            const int nsub = wv + j * 4;
            if (nsub < nreal) {
                bf16x8 bfr = *(const bf16x8*)&Bl[nsub * 16 * BK + foff];
                #pragma unroll
                for (int s = 0; s < 4; ++s)
                    acc[s][j] = __builtin_amdgcn_mfma_f32_16x16x32_bf16(af[s], bfr, acc[s][j], 0, 0, 0);
            }
        }
    }

    const size_t hbase = (size_t)e * CAP + n0;
    #pragma unroll
    for (int s = 0; s < 4; ++s) {
        const int rowb = mtile * 64 + s * 16 + qd * 4;   // even
        const float4 bv = *(const float4*)(b1 + e * 2048 + rowb);
        #pragma unroll
        for (int j = 0; j < 3; ++j) {
            const int nsub = wv + j * 4;
            const int slot = nsub * 16 + mr;
            if (nsub < nreal && slot < MeL) {
                f32x4v v = acc[s][j];
                const float wt = wgtL[slot];
                float g0 = v[0] + bv.x, l0 = v[1] + bv.y;
                float g1 = v[2] + bv.z, l1 = v[3] + bv.w;
                g0 = fminf(g0, 7.f);
                g1 = fminf(g1, 7.f);
                l0 = fminf(fmaxf(l0, -7.f), 7.f);
                l1 = fminf(fmaxf(l1, -7.f), 7.f);
                const float h0 = g0 * (1.f / (1.f + __expf(-1.702f * g0))) * (l0 + 1.f) * wt;
                const float h1 = g1 * (1.f / (1.f + __expf(-1.702f * g1))) * (l1 + 1.f) * wt;
                bf16x2 hv = { (__bf16)h0, (__bf16)h1 };
                *(bf16x2*)(h + (hbase + slot) * FF + (rowb >> 1)) = hv;
            }
        }
    }
}

// ---------------- mlp2: h2[e,slot,:] = h @ w2[e]^T (no atomics) ----------------
__global__ __launch_bounds__(256, 3) void k_mlp2(
    const float* __restrict__ w2, const __bf16* __restrict__ h,
    const int* __restrict__ cnt, float* __restrict__ h2)
{
    const int mtile = blockIdx.x;   // 16 tiles x 64 out-cols
    const int e     = blockIdx.y;
    const int ntile = blockIdx.z;
    const int tid   = threadIdx.x;

    int Me = cnt[e]; Me = Me > CAP ? CAP : Me;
    const int n0 = ntile * TN;
    if (n0 >= Me) return;
    int MeL = Me - n0; MeL = MeL > TN ? TN : MeL;
    const int nreal = (MeL + 15) >> 4;

    __shared__ __bf16 Al[64 * BK];
    __shared__ __bf16 Bl[TN * BK];

    const bool bval = (tid < TN) && (n0 + tid < CAP);
    const __bf16* hrow = h + ((size_t)e * CAP + n0 + tid) * FF;

    f32x4v acc[4][3];
    #pragma unroll
    for (int s = 0; s < 4; ++s)
        #pragma unroll
        for (int j = 0; j < 3; ++j)
            #pragma unroll
            for (int q = 0; q < 4; ++q) acc[s][j][q] = 0.f;

    const int arow = tid >> 2, aq = tid & 3;
    const int ars  = (arow >> 1) & 3;
    const int rs   = (tid >> 1) & 3;
    const int lane = tid & 63, wv = tid >> 6;
    const int mr = lane & 15, qd = lane >> 4;
    const int foff = mr * BK + ((qd ^ ((mr >> 1) & 3)) << 3);
    const float* aptr = w2 + ((size_t)e * HH + (size_t)mtile * 64 + arow) * FF + aq * 8;

    float4 pa0, pa1;
    uint4  pb0, pb1, pb2, pb3;
    pa0 = ((const float4*)aptr)[0];
    pa1 = ((const float4*)aptr)[1];
    if (bval) {
        const uint4* bs = (const uint4*)hrow;
        pb0 = bs[0]; pb1 = bs[1]; pb2 = bs[2]; pb3 = bs[3];
    }

    for (int ks = 0; ks < 32; ++ks) {
        __syncthreads();
        {
            bf16x8 p0;
            p0[0]=(__bf16)pa0.x; p0[1]=(__bf16)pa0.y; p0[2]=(__bf16)pa0.z; p0[3]=(__bf16)pa0.w;
            p0[4]=(__bf16)pa1.x; p0[5]=(__bf16)pa1.y; p0[6]=(__bf16)pa1.z; p0[7]=(__bf16)pa1.w;
            *(bf16x8*)&Al[arow * BK + ((aq ^ ars) << 3)] = p0;
        }
        if (tid < TN) {
            uint4 c0 = bval ? pb0 : uint4{0,0,0,0};
            uint4 c1 = bval ? pb1 : uint4{0,0,0,0};
            uint4 c2 = bval ? pb2 : uint4{0,0,0,0};
            uint4 c3 = bval ? pb3 : uint4{0,0,0,0};
            *(uint4*)&Bl[tid * BK + ((0 ^ rs) << 3)] = c0;
            *(uint4*)&Bl[tid * BK + ((1 ^ rs) << 3)] = c1;
            *(uint4*)&Bl[tid * BK + ((2 ^ rs) << 3)] = c2;
            *(uint4*)&Bl[tid * BK + ((3 ^ rs) << 3)] = c3;
        }
        __syncthreads();
        if (ks < 31) {
            const float4* s2 = (const float4*)(aptr + (ks + 1) * BK);
            pa0 = s2[0]; pa1 = s2[1];
            if (bval) {
                const uint4* bs = (const uint4*)(hrow + (ks + 1) * BK);
                pb0 = bs[0]; pb1 = bs[1]; pb2 = bs[2]; pb3 = bs[3];
            }
        }
        bf16x8 af[4];
        #pragma unroll
        for (int s = 0; s < 4; ++s) af[s] = *(const bf16x8*)&Al[s * 16 * BK + foff];
        #pragma unroll
        for (int j = 0; j < 3; ++j) {
            const int nsub = wv + j * 4;
            if (nsub < nreal) {
                bf16x8 bfr = *(const bf16x8*)&Bl[nsub * 16 * BK + foff];
                #pragma unroll
                for (int s = 0; s < 4; ++s)
                    acc[s][j] = __builtin_amdgcn_mfma_f32_16x16x32_bf16(af[s], bfr, acc[s][j], 0, 0, 0);
            }
        }
    }

    #pragma unroll
    for (int s = 0; s < 4; ++s) {
        const int colb = mtile * 64 + s * 16 + qd * 4;
        #pragma unroll
        for (int j = 0; j < 3; ++j) {
            const int nsub = wv + j * 4;
            const int slot = nsub * 16 + mr;
            if (nsub < nreal && slot < MeL) {
                f32x4v v = acc[s][j];
                float4 ov; ov.x = v[0]; ov.y = v[1]; ov.z = v[2]; ov.w = v[3];
                *(float4*)&h2[((size_t)e * CAP + n0 + slot) * HH + colb] = ov;
            }
        }
    }
}

// ---------------- combine: out = x + sum_k (h2[e_k,pos_k,:] + w_k*b2[e_k,:]) ----------------
__global__ __launch_bounds__(256) void k_combine(
    const float* __restrict__ x, const float* __restrict__ b2,
    const float* __restrict__ h2, const int* __restrict__ res,
    const float* __restrict__ rw, float* __restrict__ out)
{
    const int t = blockIdx.x, tid = threadIdx.x;
    float4 acc = ((const float4*)(x + (size_t)t * HH))[tid];
    #pragma unroll
    for (int k = 0; k < NK; ++k) {
        const int es = res[t * NK + k];
        const float wt = rw[t * NK + k];
        const int e = es >> 16, pos = es & 0xffff;
        if (pos < CAP) {
            float4 hv = ((const float4*)(h2 + ((size_t)e * CAP + pos) * HH))[tid];
            float4 bv = ((const float4*)(b2 + (size_t)e * HH))[tid];
            acc.x += hv.x + wt * bv.x;
            acc.y += hv.y + wt * bv.y;
            acc.z += hv.z + wt * bv.z;
            acc.w += hv.w + wt * bv.w;
        }
    }
    ((float4*)(out + (size_t)t * HH))[tid] = acc;
}

extern "C" void kernel_launch(void* const* d_in, const int* in_sizes, int n_in,
                              void* d_out, int out_size, void* d_ws, size_t ws_size,
                              hipStream_t stream) {
    const float* x      = (const float*)d_in[0];
    const float* nscale = (const float*)d_in[1];
    const float* gw     = (const float*)d_in[2];
    const float* gb     = (const float*)d_in[3];
    const float* w1     = (const float*)d_in[4];
    const float* b1     = (const float*)d_in[5];
    const float* w2     = (const float*)d_in[6];
    const float* b2     = (const float*)d_in[7];
    float* out = (float*)d_out;

    char* ws = (char*)d_ws;
    int*    cnt = (int*)(ws);
    int*    tok = (int*)(ws + OFF_TOK);
    float*  wgt = (float*)(ws + OFF_WGT);
    int*    res = (int*)(ws + OFF_ES);
    float*  rw  = (float*)(ws + OFF_RW);
    __bf16* tbf = (__bf16*)(ws + OFF_T);
    __bf16* h   = (__bf16*)(ws + OFF_H);
    float*  h2  = (float*)(ws + OFF_H2);

    k_zero<<<1, 64, 0, stream>>>(cnt);
    k_router<<<1024, 256, 0, stream>>>(x, nscale, gw, gb, tbf, cnt, tok, wgt, res, rw);
    k_mlp1<<<dim3(32, 32, 2), 256, 0, stream>>>(w1, b1, tbf, cnt, tok, wgt, h);
    k_mlp2<<<dim3(16, 32, 2), 256, 0, stream>>>(w2, h, cnt, h2);
    k_combine<<<1024, 256, 0, stream>>>(x, b2, h2, res, rw, out);
}

// Round 3
// 555.161 us; speedup vs baseline: 1.0876x; 1.0111x over previous
//
#include <hip/hip_runtime.h>
#include <hip/hip_bf16.h>
#include <stdint.h>

#define HH   1024
#define FF   1024
#define NE   32
#define NK   4
#define CAP  256
#define BK   32
#define TN   192

typedef __bf16 bf16x8 __attribute__((ext_vector_type(8)));
typedef __bf16 bf16x4 __attribute__((ext_vector_type(4)));
typedef __bf16 bf16x2 __attribute__((ext_vector_type(2)));
typedef float  f32x4v __attribute__((ext_vector_type(4)));

// ---------------- workspace layout (bytes) ----------------
#define OFF_TOK 1024        // 32*256*4 = 32 KiB
#define OFF_WGT 33792       // 32 KiB
#define OFF_ES  66560       // 16 KiB (packed e<<16|pos per token,k)
#define OFF_RW  82944       // 16 KiB (routing weight per token,k)
#define OFF_T   131072      // 2 MiB  bf16 t
#define OFF_H   2228224     // 16 MiB bf16 h (mlp1 out)
#define OFF_H2  19005440    // 16 MiB bf16 h2 (mlp2 out)

__global__ void k_zero(int* __restrict__ cnt) {
    if (threadIdx.x < NE) cnt[threadIdx.x] = 0;
}

// ---------------- router: rmsnorm + gate + top4 + lists ----------------
__global__ __launch_bounds__(256) void k_router(
    const float* __restrict__ x, const float* __restrict__ nscale,
    const float* __restrict__ gw, const float* __restrict__ gb,
    __bf16* __restrict__ tbf, int* __restrict__ cnt,
    int* __restrict__ tok, float* __restrict__ wgt,
    int* __restrict__ res, float* __restrict__ rw)
{
    const int t = blockIdx.x, tid = threadIdx.x;
    __shared__ float tl[HH];
    __shared__ float red[4];
    __shared__ float logits[NE];

    float4 xv = ((const float4*)(x + (size_t)t * HH))[tid];
    float ss = xv.x * xv.x + xv.y * xv.y + xv.z * xv.z + xv.w * xv.w;
    #pragma unroll
    for (int o = 32; o; o >>= 1) ss += __shfl_xor(ss, o);
    if ((tid & 63) == 0) red[tid >> 6] = ss;
    __syncthreads();
    const float mean = (red[0] + red[1] + red[2] + red[3]) * (1.0f / HH);
    const float r = rsqrtf(mean + 1e-5f);
    float4 sc = ((const float4*)nscale)[tid];
    float4 tv;
    tv.x = xv.x * r * sc.x; tv.y = xv.y * r * sc.y;
    tv.z = xv.z * r * sc.z; tv.w = xv.w * r * sc.w;

    ((float4*)tl)[tid] = tv;
    bf16x4 pv = { (__bf16)tv.x, (__bf16)tv.y, (__bf16)tv.z, (__bf16)tv.w };
    *(bf16x4*)(tbf + (size_t)t * HH + tid * 4) = pv;
    __syncthreads();

    const int e = tid >> 3, q = tid & 7;
    const float4* gr = (const float4*)(gw + e * HH + q * 128);
    const float4* tr = (const float4*)(tl + q * 128);
    float s = 0.f;
    #pragma unroll 8
    for (int j = 0; j < 32; ++j) {
        float4 g = gr[j], v = tr[j];
        s += g.x * v.x + g.y * v.y + g.z * v.z + g.w * v.w;
    }
    s += __shfl_xor(s, 1); s += __shfl_xor(s, 2); s += __shfl_xor(s, 4);
    if (q == 0) logits[e] = s + gb[e];
    __syncthreads();

    if (tid == 0) {
        float v[NK]; int id[NK]; unsigned used = 0;
        for (int k = 0; k < NK; ++k) {
            float best = -1e30f; int bi = 0;
            for (int ee = 0; ee < NE; ++ee)
                if (!((used >> ee) & 1u) && logits[ee] > best) { best = logits[ee]; bi = ee; }
            used |= 1u << bi; v[k] = best; id[k] = bi;
        }
        float ex[NK], se = 0.f;
        for (int k = 0; k < NK; ++k) { ex[k] = __expf(v[k] - v[0]); se += ex[k]; }
        const float inv = 1.0f / se;
        for (int k = 0; k < NK; ++k) {
            const float wk = ex[k] * inv;
            int pos = atomicAdd(&cnt[id[k]], 1);
            if (pos < CAP) {
                tok[id[k] * CAP + pos] = t;
                wgt[id[k] * CAP + pos] = wk;
            }
            res[t * NK + k] = (id[k] << 16) | (pos & 0xffff);
            rw[t * NK + k] = wk;
        }
    }
}

// ---------------- mlp1: h = swiglu(t @ w1[e]^T + b1) * route_w ----------------
// 64 w1-rows x 192 slots, reg prefetch + LDS double-buffer, 1 barrier/step.
__global__ __launch_bounds__(256, 3) void k_mlp1(
    const float* __restrict__ w1, const float* __restrict__ b1,
    const __bf16* __restrict__ tbf, const int* __restrict__ cnt,
    const int* __restrict__ tok, const float* __restrict__ wgt,
    __bf16* __restrict__ h)
{
    const int mtile = blockIdx.x;   // 32 tiles x 64 w1-rows
    const int e     = blockIdx.y;
    const int ntile = blockIdx.z;
    const int tid   = threadIdx.x;

    int Me = cnt[e]; Me = Me > CAP ? CAP : Me;
    const int n0 = ntile * TN;
    if (n0 >= Me) return;
    int MeL = Me - n0; MeL = MeL > TN ? TN : MeL;
    const int nreal = (MeL + 15) >> 4;

    __shared__ __bf16 Al[2][64 * BK];
    __shared__ __bf16 Bl[2][TN * BK];
    __shared__ float  wgtL[TN];

    int myTok = 0;
    if (tid < TN) {
        const int sl = n0 + tid;
        float w = 0.f;
        if (sl < Me) { myTok = tok[e * CAP + sl]; w = wgt[e * CAP + sl]; }
        wgtL[tid] = w;
    }

    f32x4v acc[4][3];
    #pragma unroll
    for (int s = 0; s < 4; ++s)
        #pragma unroll
        for (int j = 0; j < 3; ++j)
            #pragma unroll
            for (int q = 0; q < 4; ++q) acc[s][j][q] = 0.f;

    const int arow = tid >> 2, aq = tid & 3;
    const int ars  = (arow >> 1) & 3;
    const int rs   = (tid >> 1) & 3;
    const int lane = tid & 63, wv = tid >> 6;
    const int mr = lane & 15, qd = lane >> 4;
    const int foff = mr * BK + ((qd ^ ((mr >> 1) & 3)) << 3);
    const float* aptr = w1 + ((size_t)e * 2048 + (size_t)mtile * 64 + arow) * HH + aq * 8;
    const __bf16* tbase = tbf + (size_t)myTok * HH;

    float4 pa0, pa1;
    uint4  pb0, pb1, pb2, pb3;
    pa0 = ((const float4*)aptr)[0];
    pa1 = ((const float4*)aptr)[1];
    if (tid < TN) {
        const uint4* bs = (const uint4*)tbase;
        pb0 = bs[0]; pb1 = bs[1]; pb2 = bs[2]; pb3 = bs[3];
    }

    for (int ks = 0; ks < 32; ++ks) {
        const int p = ks & 1;
        {
            bf16x8 p0;
            p0[0]=(__bf16)pa0.x; p0[1]=(__bf16)pa0.y; p0[2]=(__bf16)pa0.z; p0[3]=(__bf16)pa0.w;
            p0[4]=(__bf16)pa1.x; p0[5]=(__bf16)pa1.y; p0[6]=(__bf16)pa1.z; p0[7]=(__bf16)pa1.w;
            *(bf16x8*)&Al[p][arow * BK + ((aq ^ ars) << 3)] = p0;
        }
        if (tid < TN) {
            *(uint4*)&Bl[p][tid * BK + ((0 ^ rs) << 3)] = pb0;
            *(uint4*)&Bl[p][tid * BK + ((1 ^ rs) << 3)] = pb1;
            *(uint4*)&Bl[p][tid * BK + ((2 ^ rs) << 3)] = pb2;
            *(uint4*)&Bl[p][tid * BK + ((3 ^ rs) << 3)] = pb3;
        }
        if (ks < 31) {
            const float4* s2 = (const float4*)(aptr + (ks + 1) * BK);
            pa0 = s2[0]; pa1 = s2[1];
            if (tid < TN) {
                const uint4* bs = (const uint4*)(tbase + (ks + 1) * BK);
                pb0 = bs[0]; pb1 = bs[1]; pb2 = bs[2]; pb3 = bs[3];
            }
        }
        __syncthreads();
        bf16x8 af[4];
        #pragma unroll
        for (int s = 0; s < 4; ++s) af[s] = *(const bf16x8*)&Al[p][s * 16 * BK + foff];
        #pragma unroll
        for (int j = 0; j < 3; ++j) {
            const int nsub = wv + j * 4;
            if (nsub < nreal) {
                bf16x8 bfr = *(const bf16x8*)&Bl[p][nsub * 16 * BK + foff];
                #pragma unroll
                for (int s = 0; s < 4; ++s)
                    acc[s][j] = __builtin_amdgcn_mfma_f32_16x16x32_bf16(af[s], bfr, acc[s][j], 0, 0, 0);
            }
        }
    }

    const size_t hbase = (size_t)e * CAP + n0;
    #pragma unroll
    for (int s = 0; s < 4; ++s) {
        const int rowb = mtile * 64 + s * 16 + qd * 4;   // even
        const float4 bv = *(const float4*)(b1 + e * 2048 + rowb);
        #pragma unroll
        for (int j = 0; j < 3; ++j) {
            const int nsub = wv + j * 4;
            const int slot = nsub * 16 + mr;
            if (nsub < nreal && slot < MeL) {
                f32x4v v = acc[s][j];
                const float wt = wgtL[slot];
                float g0 = v[0] + bv.x, l0 = v[1] + bv.y;
                float g1 = v[2] + bv.z, l1 = v[3] + bv.w;
                g0 = fminf(g0, 7.f);
                g1 = fminf(g1, 7.f);
                l0 = fminf(fmaxf(l0, -7.f), 7.f);
                l1 = fminf(fmaxf(l1, -7.f), 7.f);
                const float h0 = g0 * (1.f / (1.f + __expf(-1.702f * g0))) * (l0 + 1.f) * wt;
                const float h1 = g1 * (1.f / (1.f + __expf(-1.702f * g1))) * (l1 + 1.f) * wt;
                bf16x2 hv = { (__bf16)h0, (__bf16)h1 };
                *(bf16x2*)(h + (hbase + slot) * FF + (rowb >> 1)) = hv;
            }
        }
    }
}

// ---------------- mlp2: h2[e,slot,:] = h @ w2[e]^T (bf16 out, no atomics) ----------------
__global__ __launch_bounds__(256, 3) void k_mlp2(
    const float* __restrict__ w2, const __bf16* __restrict__ h,
    const int* __restrict__ cnt, __bf16* __restrict__ h2)
{
    const int mtile = blockIdx.x;   // 16 tiles x 64 out-cols
    const int e     = blockIdx.y;
    const int ntile = blockIdx.z;
    const int tid   = threadIdx.x;

    int Me = cnt[e]; Me = Me > CAP ? CAP : Me;
    const int n0 = ntile * TN;
    if (n0 >= Me) return;
    int MeL = Me - n0; MeL = MeL > TN ? TN : MeL;
    const int nreal = (MeL + 15) >> 4;

    __shared__ __bf16 Al[2][64 * BK];
    __shared__ __bf16 Bl[2][TN * BK];

    const bool bval = (tid < TN) && (n0 + tid < CAP);
    const __bf16* hrow = h + ((size_t)e * CAP + n0 + tid) * FF;

    f32x4v acc[4][3];
    #pragma unroll
    for (int s = 0; s < 4; ++s)
        #pragma unroll
        for (int j = 0; j < 3; ++j)
            #pragma unroll
            for (int q = 0; q < 4; ++q) acc[s][j][q] = 0.f;

    const int arow = tid >> 2, aq = tid & 3;
    const int ars  = (arow >> 1) & 3;
    const int rs   = (tid >> 1) & 3;
    const int lane = tid & 63, wv = tid >> 6;
    const int mr = lane & 15, qd = lane >> 4;
    const int foff = mr * BK + ((qd ^ ((mr >> 1) & 3)) << 3);
    const float* aptr = w2 + ((size_t)e * HH + (size_t)mtile * 64 + arow) * FF + aq * 8;

    float4 pa0, pa1;
    uint4  pb0 = {0,0,0,0}, pb1 = {0,0,0,0}, pb2 = {0,0,0,0}, pb3 = {0,0,0,0};
    pa0 = ((const float4*)aptr)[0];
    pa1 = ((const float4*)aptr)[1];
    if (bval) {
        const uint4* bs = (const uint4*)hrow;
        pb0 = bs[0]; pb1 = bs[1]; pb2 = bs[2]; pb3 = bs[3];
    }

    for (int ks = 0; ks < 32; ++ks) {
        const int p = ks & 1;
        {
            bf16x8 p0;
            p0[0]=(__bf16)pa0.x; p0[1]=(__bf16)pa0.y; p0[2]=(__bf16)pa0.z; p0[3]=(__bf16)pa0.w;
            p0[4]=(__bf16)pa1.x; p0[5]=(__bf16)pa1.y; p0[6]=(__bf16)pa1.z; p0[7]=(__bf16)pa1.w;
            *(bf16x8*)&Al[p][arow * BK + ((aq ^ ars) << 3)] = p0;
        }
        if (tid < TN) {
            *(uint4*)&Bl[p][tid * BK + ((0 ^ rs) << 3)] = pb0;
            *(uint4*)&Bl[p][tid * BK + ((1 ^ rs) << 3)] = pb1;
            *(uint4*)&Bl[p][tid * BK + ((2 ^ rs) << 3)] = pb2;
            *(uint4*)&Bl[p][tid * BK + ((3 ^ rs) << 3)] = pb3;
        }
        if (ks < 31) {
            const float4* s2 = (const float4*)(aptr + (ks + 1) * BK);
            pa0 = s2[0]; pa1 = s2[1];
            if (bval) {
                const uint4* bs = (const uint4*)(hrow + (ks + 1) * BK);
                pb0 = bs[0]; pb1 = bs[1]; pb2 = bs[2]; pb3 = bs[3];
            }
        }
        __syncthreads();
        bf16x8 af[4];
        #pragma unroll
        for (int s = 0; s < 4; ++s) af[s] = *(const bf16x8*)&Al[p][s * 16 * BK + foff];
        #pragma unroll
        for (int j = 0; j < 3; ++j) {
            const int nsub = wv + j * 4;
            if (nsub < nreal) {
                bf16x8 bfr = *(const bf16x8*)&Bl[p][nsub * 16 * BK + foff];
                #pragma unroll
                for (int s = 0; s < 4; ++s)
                    acc[s][j] = __builtin_amdgcn_mfma_f32_16x16x32_bf16(af[s], bfr, acc[s][j], 0, 0, 0);
            }
        }
    }

    #pragma unroll
    for (int s = 0; s < 4; ++s) {
        const int colb = mtile * 64 + s * 16 + qd * 4;
        #pragma unroll
        for (int j = 0; j < 3; ++j) {
            const int nsub = wv + j * 4;
            const int slot = nsub * 16 + mr;
            if (nsub < nreal && slot < MeL) {
                f32x4v v = acc[s][j];
                bf16x4 ov = { (__bf16)v[0], (__bf16)v[1], (__bf16)v[2], (__bf16)v[3] };
                *(bf16x4*)&h2[((size_t)e * CAP + n0 + slot) * HH + colb] = ov;
            }
        }
    }
}

// ---------------- combine: out = x + sum_k (h2[e_k,pos_k,:] + w_k*b2[e_k,:]) ----------------
__global__ __launch_bounds__(256) void k_combine(
    const float* __restrict__ x, const float* __restrict__ b2,
    const __bf16* __restrict__ h2, const int* __restrict__ res,
    const float* __restrict__ rw, float* __restrict__ out)
{
    const int t = blockIdx.x, tid = threadIdx.x;
    float4 acc = ((const float4*)(x + (size_t)t * HH))[tid];
    #pragma unroll
    for (int k = 0; k < NK; ++k) {
        const int es = res[t * NK + k];
        const float wt = rw[t * NK + k];
        const int e = es >> 16, pos = es & 0xffff;
        if (pos < CAP) {
            bf16x4 hv = *(const bf16x4*)(h2 + ((size_t)e * CAP + pos) * HH + tid * 4);
            float4 bv = ((const float4*)(b2 + (size_t)e * HH))[tid];
            acc.x += (float)hv[0] + wt * bv.x;
            acc.y += (float)hv[1] + wt * bv.y;
            acc.z += (float)hv[2] + wt * bv.z;
            acc.w += (float)hv[3] + wt * bv.w;
        }
    }
    ((float4*)(out + (size_t)t * HH))[tid] = acc;
}

extern "C" void kernel_launch(void* const* d_in, const int* in_sizes, int n_in,
                              void* d_out, int out_size, void* d_ws, size_t ws_size,
                              hipStream_t stream) {
    const float* x      = (const float*)d_in[0];
    const float* nscale = (const float*)d_in[1];
    const float* gw     = (const float*)d_in[2];
    const float* gb     = (const float*)d_in[3];
    const float* w1     = (const float*)d_in[4];
    const float* b1     = (const float*)d_in[5];
    const float* w2     = (const float*)d_in[6];
    const float* b2     = (const float*)d_in[7];
    float* out = (float*)d_out;

    char* ws = (char*)d_ws;
    int*    cnt = (int*)(ws);
    int*    tok = (int*)(ws + OFF_TOK);
    float*  wgt = (float*)(ws + OFF_WGT);
    int*    res = (int*)(ws + OFF_ES);
    float*  rw  = (float*)(ws + OFF_RW);
    __bf16* tbf = (__bf16*)(ws + OFF_T);
    __bf16* h   = (__bf16*)(ws + OFF_H);
    __bf16* h2  = (__bf16*)(ws + OFF_H2);

    k_zero<<<1, 64, 0, stream>>>(cnt);
    k_router<<<1024, 256, 0, stream>>>(x, nscale, gw, gb, tbf, cnt, tok, wgt, res, rw);
    k_mlp1<<<dim3(32, 32, 2), 256, 0, stream>>>(w1, b1, tbf, cnt, tok, wgt, h);
    k_mlp2<<<dim3(16, 32, 2), 256, 0, stream>>>(w2, h, cnt, h2);
    k_combine<<<1024, 256, 0, stream>>>(x, b2, h2, res, rw, out);
}